// Round 16
// baseline (223.610 us; speedup 1.0000x reference)
//
#include <hip/hip_runtime.h>
#include <hip/hip_bf16.h>

#define BATCH   32768
#define DM      1024
#define NE      16
#define THRESHF 0.3f
#define MARGIN  0.02f

// ws layout (bytes)
// idx   @ 0          : int32[32768]            = 131072
// ctrl  @ 131072     : u32[2048]
//    [e*16] counts | [256+e*16] cursor | [1024..2047] packT
// Qbf   @ 139264     : bf16[16*1024] ternary   = 32768
// perm  @ 172032     : int32[36864]            (prefilled 0)
// X8    @ 319488     : fp8[32768*1024]         = 33554432
// W8    @ 33873920   : fp8[16*1024*1024]       = 16777216  (ends ~50.7 MB)
#define CTRL_OFF 131072
#define QBF_OFF  139264
#define PERM_OFF 172032
#define X8_OFF   319488
#define W8_OFF   33873920ull
#define WS_NEED  (W8_OFF + (size_t)NE * DM * DM)

typedef __attribute__((ext_vector_type(8))) short bf16x8;
typedef __attribute__((ext_vector_type(4))) float f32x4;

#define MFMA16(a, b, c)  __builtin_amdgcn_mfma_f32_16x16x32_bf16(a, b, c, 0, 0, 0)
#define MFMAF8(a, b, c)  __builtin_amdgcn_mfma_f32_16x16x32_fp8_fp8(a, b, c, 0, 0, 0)

static __device__ __forceinline__ unsigned short f2bf(float f) {
    union { float f; unsigned u; } v; v.f = f;
    unsigned r = (v.u + 0x7FFFu + ((v.u >> 16) & 1u)) >> 16;  // RNE
    return (unsigned short)r;
}
static __device__ __forceinline__ float bf2f(unsigned short h) {
    union { unsigned u; float f; } v; v.u = ((unsigned)h) << 16;
    return v.f;
}

// f32 -> fp8 e4m3fn (OCP), RNE, saturate to 448, correct subnormals.
static __device__ __forceinline__ unsigned f2fp8(float f) {
    union { float f; unsigned u; } v; v.f = f;
    const unsigned s = (v.u >> 24) & 0x80u;
    const float a = __builtin_fabsf(f);
    if (a >= 448.0f) return s | 0x7Eu;
    if (a < 0.015625f) {                       // subnormal: multiples of 2^-9
        const int n = (int)rintf(a * 512.0f);  // 0..8
        return s | (unsigned)n;                // n==8 encodes 2^-6 (exp=1,m=0)
    }
    unsigned u = v.u;
    u += 0x7FFFFu + ((u >> 20) & 1u);          // RNE at 3-bit mantissa
    const int e = (int)((u >> 23) & 0xFF) - 127;
    const unsigned m = (u >> 20) & 7u;
    return s | ((unsigned)(e + 7) << 3) | m;
}

static __device__ __forceinline__ void gload_lds16(const void* g, void* s) {
    __builtin_amdgcn_global_load_lds(
        (const __attribute__((address_space(1))) void*)g,
        (__attribute__((address_space(3))) void*)s, 16, 0, 0);
}

// Local tile-base from final counts: 16 adds.
static __device__ __forceinline__ int tile_base(const unsigned* ctrl, int* tb) {
    int acc = 0;
#pragma unroll
    for (int e = 0; e < NE; ++e) {
        tb[e] = acc;
        acc += (int)((ctrl[e * 16] + 127u) >> 7);
    }
    tb[NE] = acc;
    return acc;
}

// Zero ctrl, build ternary pack table + bf16 ternary Q, prefill perm with 0.
__global__ void k_init(const float* __restrict__ sig, unsigned* __restrict__ ctrl,
                       int* __restrict__ perm, unsigned short* __restrict__ Qbf) {
    const int t = blockIdx.x * 256 + threadIdx.x;  // 0..16383
    if (t < 544) ctrl[t] = 0;
    if (t < 1024) {
        unsigned pm = 0, mm = 0;
#pragma unroll
        for (int e = 0; e < NE; ++e) {
            float s = sig[e * DM + t];
            pm |= (s > THRESHF ? 1u : 0u) << e;
            mm |= (s < -THRESHF ? 1u : 0u) << e;
        }
        ctrl[1024 + t] = pm | (mm << 16);
    }
    if (t < 9216) ((int4*)perm)[t] = make_int4(0, 0, 0, 0);
    {
        float s = sig[t];
        Qbf[t] = s > THRESHF ? (unsigned short)0x3F80u
                             : (s < -THRESHF ? (unsigned short)0xBF80u : (unsigned short)0u);
    }
}

// Split-K MFMA router (R11 structure; Qbf table read — R14 lesson). Writes
// X8 (fp8 of x) instead of Xbf: GEMM A is fp8; residual reads x f32 directly.
__global__ __launch_bounds__(256) void k_router(const float* __restrict__ x,
                                                const unsigned short* __restrict__ Qbf,
                                                unsigned* __restrict__ ctrl,
                                                int* __restrict__ idx,
                                                float* __restrict__ outIdx,
                                                unsigned char* __restrict__ X8,
                                                int writeX8) {
    __shared__ float S[4][64][4];
    const int t = threadIdx.x, w = t >> 6, l = t & 63;
    const int lc = l & 15, lr = l >> 4;
    const int row0 = blockIdx.x * 16;
    const unsigned* packT = ctrl + 1024;

    const float* ax = x + (size_t)(row0 + lc) * DM + lr * 8;
    const unsigned short* qx = Qbf + (size_t)lc * DM + lr * 8;
    unsigned char* xb = X8 + (size_t)(row0 + lc) * DM + lr * 8;

    f32x4 acc = (f32x4){0.f, 0.f, 0.f, 0.f};

    for (int kt = w * 4; kt < w * 4 + 4; ++kt) {
#pragma unroll
        for (int h = 0; h < 2; ++h) {
            const int ko = kt * 64 + h * 32;
            float4 v0 = *(const float4*)(ax + ko);
            float4 v1 = *(const float4*)(ax + ko + 4);
            bf16x8 q = *(const bf16x8*)(qx + ko);

            float f[8] = {v0.x, v0.y, v0.z, v0.w, v1.x, v1.y, v1.z, v1.w};
            bf16x8 ah, al;
            unsigned long long p8 = 0ull;
#pragma unroll
            for (int j = 0; j < 8; ++j) {
                unsigned short hi = f2bf(f[j]);
                float r = f[j] - bf2f(hi);
                ah[j] = (short)hi;
                al[j] = (short)f2bf(r);
                p8 |= (unsigned long long)f2fp8(f[j]) << (8 * j);
            }
            if (writeX8) *(unsigned long long*)(xb + ko) = p8;
            acc = MFMA16(ah, q, acc);
            acc = MFMA16(al, q, acc);
        }
    }

    *(f32x4*)&S[w][l][0] = acc;
    __syncthreads();
    if (w != 0) return;

#pragma unroll
    for (int s = 1; s < 4; ++s) acc += *(const f32x4*)&S[s][l][0];

    float bv[4]; int bi[4]; float gap[4];
#pragma unroll
    for (int reg = 0; reg < 4; ++reg) {
        float v = acc[reg]; int i = lc; float s = -3.4e38f;
#pragma unroll
        for (int m = 1; m < 16; m <<= 1) {
            float ov = __shfl_xor(v, m, 64);
            int oi = __shfl_xor(i, m, 64);
            float os = __shfl_xor(s, m, 64);
            bool take = (ov > v) || (ov == v && oi < i);
            float loser = take ? v : ov;
            v = take ? ov : v;
            i = take ? oi : i;
            s = fmaxf(fmaxf(s, os), loser);
        }
        bv[reg] = v; bi[reg] = i; gap[reg] = v - s;
    }

    unsigned flagsw = 0;
#pragma unroll
    for (int reg = 0; reg < 4; ++reg)
        flagsw |= (gap[reg] < MARGIN ? 1u : 0u) << reg;

    if (__any(lc == 0 && flagsw != 0)) {   // rare exact path
#pragma unroll
        for (int reg = 0; reg < 4; ++reg) {
            for (int g = 0; g < 4; ++g) {
                const unsigned fw = __shfl(flagsw, g * 16, 64);
                if ((fw >> reg) & 1u) {
                    const int row = row0 + g * 4 + reg;
                    const float* xr = x + (size_t)row * DM;
                    float xv[16]; unsigned mk[16];
#pragma unroll
                    for (int k2 = 0; k2 < 16; ++k2) {
                        xv[k2] = xr[k2 * 64 + l];
                        mk[k2] = packT[k2 * 64 + l];
                    }
                    double best = 0.0; int bbi = 0;
                    for (int e = 0; e < 16; ++e) {
                        double a = 0.0;
#pragma unroll
                        for (int k2 = 0; k2 < 16; ++k2) {
                            const int pb = (int)((mk[k2] >> e) & 1u);
                            const int mb = (int)((mk[k2] >> (16 + e)) & 1u);
                            a += pb ? (double)xv[k2] : (mb ? -(double)xv[k2] : 0.0);
                        }
#pragma unroll
                        for (int m = 1; m < 64; m <<= 1) a += __shfl_xor(a, m, 64);
                        if (e == 0 || a > best) { best = a; bbi = e; }
                    }
                    if (lr == g && lc == 0) bi[reg] = bbi;
                }
            }
        }
    }

    if (lc == 0) {
#pragma unroll
        for (int reg = 0; reg < 4; ++reg) {
            const int row = row0 + lr * 4 + reg;
            idx[row] = bi[reg];
            outIdx[row] = (float)bi[reg];
            atomicAdd(&ctrl[bi[reg] * 16], 1u);
        }
    }
}

// Fused: blocks 0..127 build perm; blocks 128.. convert W f32 -> fp8 (x16
// scale: |16W| <= 0.5 stays in e4m3 normal range; GEMM epilogue * 1/16).
__global__ __launch_bounds__(256) void k_permconv(const int* __restrict__ idx,
                                                  unsigned* __restrict__ ctrl,
                                                  int* __restrict__ perm,
                                                  const float* __restrict__ W,
                                                  unsigned char* __restrict__ W8) {
    if (blockIdx.x >= 128) {
        const size_t g = ((size_t)(blockIdx.x - 128) * 256 + threadIdx.x) * 8;
        float4 a = *(const float4*)&W[g];
        float4 b = *(const float4*)&W[g + 4];
        float f[8] = {a.x, a.y, a.z, a.w, b.x, b.y, b.z, b.w};
        unsigned long long p8 = 0ull;
#pragma unroll
        for (int j = 0; j < 8; ++j)
            p8 |= (unsigned long long)f2fp8(f[j] * 16.0f) << (8 * j);
        *(unsigned long long*)(W8 + g) = p8;
        return;
    }
    __shared__ unsigned hcnt[16];
    __shared__ unsigned hbase[16];
    const int t = threadIdx.x;
    const int row = blockIdx.x * 256 + t;
    int tb[NE + 1];
    tile_base(ctrl, tb);
    if (t < 16) hcnt[t] = 0;
    __syncthreads();
    const int e = idx[row];
    const unsigned lrank = atomicAdd(&hcnt[e], 1u);
    __syncthreads();
    if (t < 16) hbase[t] = atomicAdd(&ctrl[256 + t * 16], hcnt[t]);
    __syncthreads();
    perm[tb[e] * 128 + hbase[e] + lrank] = row;
}

// Grouped fp8 GEMM (R16): R7 sync skeleton VERBATIM (3 buffers depth-2,
// counted vmcnt(4), 1 barrier/iter, 3 blk/CU) but fp8 e4m3 operands with
// BK=64: staged bytes AND 64B-line transactions per K-element halved, and
// NT 32->16 halves barrier count. MFMA 16x16x32_fp8_fp8 (bf16 rate) x2 ks.
// LDS [128][64B] per tile; 16B-slot swizzle: slot s of row r holds data
// chunk (s - ((r>>1)&3))&3 (both-sides, lane-linear dest; 2 lanes/bank=free).
// Epilogue: acc*(1/16) + bias, ReLU, + exact f32 x residual.
__global__ __launch_bounds__(256) void k_gemm(
        const unsigned char* __restrict__ X8,
        const unsigned char* __restrict__ W8,
        const float* __restrict__ bias,
        const int* __restrict__ perm,
        const unsigned* __restrict__ ctrl,
        const float* __restrict__ x,
        float* __restrict__ out) {
    __shared__ unsigned char A_lds[3][8192];
    __shared__ unsigned char B_lds[3][8192];

    int tb[NE + 1];
    const int total = tile_base(ctrl, tb);

    // flat = 0..2175: xcd = flat&7; all 8 ny-siblings of one bx share an XCD.
    int bx, ny;
    {
        const int flat = blockIdx.x;
        const int xcd = flat & 7, s2 = flat >> 3;
        bx = xcd * 34 + (s2 >> 3);
        ny = s2 & 7;
    }
    if (bx >= total) return;
    int e = 0;
    while (e < NE - 1 && tb[e + 1] <= bx) ++e;
    const int valid = (int)ctrl[e * 16] - (bx - tb[e]) * 128;  // 1..128
    const int n0 = ny * 128;

    const int t = threadIdx.x, w = t >> 6, l = t & 63;
    const int wr = w >> 1, wc = w & 1;
    const int lc = l & 15, lr = l >> 4;
    const int hsw = ((t & 3) - ((t >> 3) & 3)) & 3;   // staged global chunk16
    const int d4b = lr >> 1, off8 = (lr & 1) * 8;     // read chunk decomposition

    f32x4 acc[4][4];
#pragma unroll
    for (int m = 0; m < 4; ++m)
#pragma unroll
        for (int n = 0; n < 4; ++n) acc[m][n] = (f32x4){0.f, 0.f, 0.f, 0.f};

    const size_t aRowBase = (size_t)bx * 128;
    const unsigned char* Bg = W8 + ((size_t)e * DM + n0) * DM;

    const int r0 = t >> 2;
    const int prow0 = perm[aRowBase + r0];
    const int prow1 = perm[aRowBase + 64 + r0];
    const unsigned char* a0 = X8 + (size_t)prow0 * DM + hsw * 16;
    const unsigned char* a1 = X8 + (size_t)prow1 * DM + hsw * 16;
    const unsigned char* b0 = Bg + (size_t)r0 * DM + hsw * 16;
    const unsigned char* b1 = Bg + (size_t)(64 + r0) * DM + hsw * 16;

    auto STAGE = [&](int kt, int buf) {   // 4 VMEM ops/thread (as R7)
        const int ko = kt * 64;
        gload_lds16(a0 + ko, &A_lds[buf][w * 1024]);
        gload_lds16(a1 + ko, &A_lds[buf][4096 + w * 1024]);
        gload_lds16(b0 + ko, &B_lds[buf][w * 1024]);
        gload_lds16(b1 + ko, &B_lds[buf][4096 + w * 1024]);
    };

    STAGE(0, 0);
    STAGE(1, 1);

    const int NT = DM / 64;  // 16
    int cur = 0;
    for (int kt = 0; kt < NT; ++kt) {
        if (kt + 1 < NT) asm volatile("s_waitcnt vmcnt(4)" ::: "memory");
        else             asm volatile("s_waitcnt vmcnt(0)" ::: "memory");
        __builtin_amdgcn_sched_barrier(0);
        __builtin_amdgcn_s_barrier();
        __builtin_amdgcn_sched_barrier(0);

        if (kt + 2 < NT) {
            const int nb = (cur + 2 >= 3) ? cur - 1 : cur + 2;
            STAGE(kt + 2, nb);
        }

#pragma unroll
        for (int ks = 0; ks < 2; ++ks) {
            long af[4], bf[4];
#pragma unroll
            for (int m = 0; m < 4; ++m) {
                const int r = wr * 64 + m * 16 + lc;
                af[m] = *(const long*)&A_lds[cur][r * 64 +
                        (((ks * 2 + d4b) + ((r >> 1) & 3)) & 3) * 16 + off8];
            }
#pragma unroll
            for (int n = 0; n < 4; ++n) {
                const int r = wc * 64 + n * 16 + lc;
                bf[n] = *(const long*)&B_lds[cur][r * 64 +
                        (((ks * 2 + d4b) + ((r >> 1) & 3)) & 3) * 16 + off8];
            }
#pragma unroll
            for (int m = 0; m < 4; ++m)
#pragma unroll
                for (int n = 0; n < 4; ++n)
                    acc[m][n] = MFMAF8(af[m], bf[n], acc[m][n]);
        }

        cur = (cur + 1 >= 3) ? 0 : cur + 1;
    }

    float bvv[4];
#pragma unroll
    for (int n = 0; n < 4; ++n) bvv[n] = bias[e * DM + n0 + wc * 64 + n * 16 + lc];

#pragma unroll
    for (int m = 0; m < 4; ++m) {
#pragma unroll
        for (int reg = 0; reg < 4; ++reg) {
            const int rit = wr * 64 + m * 16 + lr * 4 + reg;  // row in tile
            if (rit < valid) {
                const int orow = perm[aRowBase + rit];
                float* op = out + (size_t)orow * DM;
                const float* xr = x + (size_t)orow * DM;
#pragma unroll
                for (int n = 0; n < 4; ++n) {
                    const int col = n0 + wc * 64 + n * 16 + lc;
                    float v = acc[m][n][reg] * 0.0625f + bvv[n];
                    v = v > 0.f ? v : 0.f;
                    op[col] = v + xr[col];
                }
            }
        }
    }
}

// Fallback (small ws): 128x128 2-phase reg-staged f32->bf16.
__global__ __launch_bounds__(256) void k_gemm_small(
        const float* __restrict__ x, const float* __restrict__ W,
        const float* __restrict__ bias, const int* __restrict__ perm,
        const unsigned* __restrict__ ctrl, float* __restrict__ out) {
    __shared__ unsigned short A_lds[128 * 32];
    __shared__ unsigned short B_lds[128 * 32];
    int tb[NE + 1];
    const int total = tile_base(ctrl, tb);
    int bx, ny;
    {
        const int flat = blockIdx.x;
        const int xcd = flat & 7, s2 = flat >> 3;
        bx = xcd * 34 + (s2 >> 3);
        ny = s2 & 7;
    }
    if (bx >= total) return;
    int e = 0;
    while (e < NE - 1 && tb[e + 1] <= bx) ++e;
    const int valid = (int)ctrl[e * 16] - (bx - tb[e]) * 128;
    const int n0 = ny * 128;
    const int t = threadIdx.x, w = t >> 6, l = t & 63;
    const int wr = w >> 1, wc = w & 1;
    const int lc = l & 15, lr = l >> 4;
    const int hsw = ((t & 3) - ((t >> 3) & 3)) & 3;
    const int ssw = (lr + (lc >> 1)) & 3;

    f32x4 acc[4][4];
#pragma unroll
    for (int m = 0; m < 4; ++m)
#pragma unroll
        for (int n = 0; n < 4; ++n) acc[m][n] = (f32x4){0.f, 0.f, 0.f, 0.f};
    const size_t aRowBase = (size_t)bx * 128;

    for (int kt = 0; kt < DM / 32; ++kt) {
        __syncthreads();
#pragma unroll
        for (int rd = 0; rd < 2; ++rd) {
            const int c = rd * 256 + t;
            const int r = c >> 2;
            const float* wp = W + ((size_t)e * DM + n0 + r) * DM + kt * 32 + hsw * 8;
            float4 q0 = *(const float4*)wp;
            float4 q1 = *(const float4*)(wp + 4);
            *(ushort4*)&B_lds[c * 8]     = make_ushort4(f2bf(q0.x), f2bf(q0.y), f2bf(q0.z), f2bf(q0.w));
            *(ushort4*)&B_lds[c * 8 + 4] = make_ushort4(f2bf(q1.x), f2bf(q1.y), f2bf(q1.z), f2bf(q1.w));
            ushort4 p0 = make_ushort4(0, 0, 0, 0), p1 = p0;
            if (r < valid) {
                const int orow = perm[aRowBase + r];
                const float* xp = x + (size_t)orow * DM + kt * 32 + hsw * 8;
                float4 u0 = *(const float4*)xp;
                float4 u1 = *(const float4*)(xp + 4);
                p0 = make_ushort4(f2bf(u0.x), f2bf(u0.y), f2bf(u0.z), f2bf(u0.w));
                p1 = make_ushort4(f2bf(u1.x), f2bf(u1.y), f2bf(u1.z), f2bf(u1.w));
            }
            *(ushort4*)&A_lds[c * 8]     = p0;
            *(ushort4*)&A_lds[c * 8 + 4] = p1;
        }
        __syncthreads();
        bf16x8 af[4], bf[4];
#pragma unroll
        for (int m = 0; m < 4; ++m)
            af[m] = *(const bf16x8*)&A_lds[(wr * 64 + m * 16 + lc) * 32 + ssw * 8];
#pragma unroll
        for (int n = 0; n < 4; ++n)
            bf[n] = *(const bf16x8*)&B_lds[(wc * 64 + n * 16 + lc) * 32 + ssw * 8];
#pragma unroll
        for (int m = 0; m < 4; ++m)
#pragma unroll
            for (int n = 0; n < 4; ++n)
                acc[m][n] = MFMA16(af[m], bf[n], acc[m][n]);
    }

    float bvv[4];
#pragma unroll
    for (int n = 0; n < 4; ++n) bvv[n] = bias[e * DM + n0 + wc * 64 + n * 16 + lc];
#pragma unroll
    for (int m = 0; m < 4; ++m)
#pragma unroll
        for (int reg = 0; reg < 4; ++reg) {
            const int rit = wr * 64 + m * 16 + lr * 4 + reg;
            if (rit < valid) {
                const int orow = perm[aRowBase + rit];
                const float* xr = x + (size_t)orow * DM;
                float* op = out + (size_t)orow * DM;
#pragma unroll
                for (int n = 0; n < 4; ++n) {
                    const int col = n0 + wc * 64 + n * 16 + lc;
                    float v = acc[m][n][reg] + bvv[n];
                    v = v > 0.f ? v : 0.f;
                    op[col] = v + xr[col];
                }
            }
        }
}

extern "C" void kernel_launch(void* const* d_in, const int* in_sizes, int n_in,
                              void* d_out, int out_size, void* d_ws, size_t ws_size,
                              hipStream_t stream) {
    const float* x    = (const float*)d_in[0];
    const float* sig  = (const float*)d_in[1];
    const float* W    = (const float*)d_in[2];
    const float* bias = (const float*)d_in[3];
    float* out = (float*)d_out;
    float* outIdx = out + (size_t)BATCH * DM;

    char* ws = (char*)d_ws;
    int* idx = (int*)ws;
    unsigned* ctrl = (unsigned*)(ws + CTRL_OFF);
    unsigned short* Qbf = (unsigned short*)(ws + QBF_OFF);
    int* perm = (int*)(ws + PERM_OFF);
    unsigned char* X8 = (unsigned char*)(ws + X8_OFF);
    unsigned char* W8 = (unsigned char*)(ws + W8_OFF);

    const bool full = ws_size >= WS_NEED;

    k_init<<<64, 256, 0, stream>>>(sig, ctrl, perm, Qbf);
    k_router<<<2048, 256, 0, stream>>>(x, Qbf, ctrl, idx, outIdx, X8, full ? 1 : 0);
    k_permconv<<<full ? 8320 : 128, 256, 0, stream>>>(idx, ctrl, perm, W, W8);
    if (full) {
        k_gemm<<<2176, 256, 0, stream>>>(X8, W8, bias, perm, ctrl, x, out);
    } else {
        k_gemm_small<<<2176, 256, 0, stream>>>(x, W, bias, perm, ctrl, out);
    }
}

// Round 17
// 217.209 us; speedup vs baseline: 1.0295x; 1.0295x over previous
//
#include <hip/hip_runtime.h>
#include <hip/hip_bf16.h>

#define BATCH   32768
#define DM      1024
#define NE      16
#define THRESHF 0.3f
#define MARGIN  0.02f

// ws layout (bytes)
// idx   @ 0          : int32[32768]
// ctrl  @ 131072     : u32[2048]  (counts | cursor | packT)
// Qbf   @ 139264     : bf16[16*1024] ternary
// perm  @ 172032     : int32[36864] (prefilled 0)
// X8    @ 319488     : fp8[32768*1024]  ks-interleaved rows
// W8    @ 33873920   : fp8[16*1024*1024] ks-interleaved rows (ends ~50.7 MB)
#define CTRL_OFF 131072
#define QBF_OFF  139264
#define PERM_OFF 172032
#define X8_OFF   319488
#define W8_OFF   33873920ull
#define WS_NEED  (W8_OFF + (size_t)NE * DM * DM)

typedef __attribute__((ext_vector_type(8))) short bf16x8;
typedef __attribute__((ext_vector_type(4))) float f32x4;
typedef __attribute__((ext_vector_type(2))) long lx2;

#define MFMA16(a, b, c)  __builtin_amdgcn_mfma_f32_16x16x32_bf16(a, b, c, 0, 0, 0)
#define MFMAF8(a, b, c)  __builtin_amdgcn_mfma_f32_16x16x32_fp8_fp8(a, b, c, 0, 0, 0)

static __device__ __forceinline__ unsigned short f2bf(float f) {
    union { float f; unsigned u; } v; v.f = f;
    unsigned r = (v.u + 0x7FFFu + ((v.u >> 16) & 1u)) >> 16;  // RNE
    return (unsigned short)r;
}
static __device__ __forceinline__ float bf2f(unsigned short h) {
    union { unsigned u; float f; } v; v.u = ((unsigned)h) << 16;
    return v.f;
}

// f32 -> fp8 e4m3fn (OCP), RNE, saturate to 448, correct subnormals.
static __device__ __forceinline__ unsigned f2fp8(float f) {
    union { float f; unsigned u; } v; v.f = f;
    const unsigned s = (v.u >> 24) & 0x80u;
    const float a = __builtin_fabsf(f);
    if (a >= 448.0f) return s | 0x7Eu;
    if (a < 0.015625f) {
        const int n = (int)rintf(a * 512.0f);
        return s | (unsigned)n;
    }
    unsigned u = v.u;
    u += 0x7FFFFu + ((u >> 20) & 1u);
    const int e = (int)((u >> 23) & 0xFF) - 127;
    const unsigned m = (u >> 20) & 7u;
    return s | ((unsigned)(e + 7) << 3) | m;
}

static __device__ __forceinline__ void gload_lds16(const void* g, void* s) {
    __builtin_amdgcn_global_load_lds(
        (const __attribute__((address_space(1))) void*)g,
        (__attribute__((address_space(3))) void*)s, 16, 0, 0);
}

// Local tile-base from final counts: 16 adds.
static __device__ __forceinline__ int tile_base(const unsigned* ctrl, int* tb) {
    int acc = 0;
#pragma unroll
    for (int e = 0; e < NE; ++e) {
        tb[e] = acc;
        acc += (int)((ctrl[e * 16] + 127u) >> 7);
    }
    tb[NE] = acc;
    return acc;
}

// Zero ctrl, build ternary pack table + bf16 ternary Q, prefill perm with 0.
__global__ void k_init(const float* __restrict__ sig, unsigned* __restrict__ ctrl,
                       int* __restrict__ perm, unsigned short* __restrict__ Qbf) {
    const int t = blockIdx.x * 256 + threadIdx.x;  // 0..16383
    if (t < 544) ctrl[t] = 0;
    if (t < 1024) {
        unsigned pm = 0, mm = 0;
#pragma unroll
        for (int e = 0; e < NE; ++e) {
            float s = sig[e * DM + t];
            pm |= (s > THRESHF ? 1u : 0u) << e;
            mm |= (s < -THRESHF ? 1u : 0u) << e;
        }
        ctrl[1024 + t] = pm | (mm << 16);
    }
    if (t < 9216) ((int4*)perm)[t] = make_int4(0, 0, 0, 0);
    {
        float s = sig[t];
        Qbf[t] = s > THRESHF ? (unsigned short)0x3F80u
                             : (s < -THRESHF ? (unsigned short)0xBF80u : (unsigned short)0u);
    }
}

// Split-K MFMA router (R11 structure; Qbf table). Writes X8 in the
// ks-interleaved layout: byte (kt*64 + ks*32 + lr*8 + h) of the row is
// stored at (kt*64 + lr*16 + ks*8 + h).
__global__ __launch_bounds__(256) void k_router(const float* __restrict__ x,
                                                const unsigned short* __restrict__ Qbf,
                                                unsigned* __restrict__ ctrl,
                                                int* __restrict__ idx,
                                                float* __restrict__ outIdx,
                                                unsigned char* __restrict__ X8,
                                                int writeX8) {
    __shared__ float S[4][64][4];
    const int t = threadIdx.x, w = t >> 6, l = t & 63;
    const int lc = l & 15, lr = l >> 4;
    const int row0 = blockIdx.x * 16;
    const unsigned* packT = ctrl + 1024;

    const float* ax = x + (size_t)(row0 + lc) * DM + lr * 8;
    const unsigned short* qx = Qbf + (size_t)lc * DM + lr * 8;
    unsigned char* xb = X8 + (size_t)(row0 + lc) * DM + lr * 16;  // permuted base

    f32x4 acc = (f32x4){0.f, 0.f, 0.f, 0.f};

    for (int kt = w * 4; kt < w * 4 + 4; ++kt) {
#pragma unroll
        for (int h = 0; h < 2; ++h) {
            const int ko = kt * 64 + h * 32;
            float4 v0 = *(const float4*)(ax + ko);
            float4 v1 = *(const float4*)(ax + ko + 4);
            bf16x8 q = *(const bf16x8*)(qx + ko);

            float f[8] = {v0.x, v0.y, v0.z, v0.w, v1.x, v1.y, v1.z, v1.w};
            bf16x8 ah, al;
            unsigned long long p8 = 0ull;
#pragma unroll
            for (int j = 0; j < 8; ++j) {
                unsigned short hi = f2bf(f[j]);
                float r = f[j] - bf2f(hi);
                ah[j] = (short)hi;
                al[j] = (short)f2bf(r);
                p8 |= (unsigned long long)f2fp8(f[j]) << (8 * j);
            }
            if (writeX8) *(unsigned long long*)(xb + kt * 64 + h * 8) = p8;
            acc = MFMA16(ah, q, acc);
            acc = MFMA16(al, q, acc);
        }
    }

    *(f32x4*)&S[w][l][0] = acc;
    __syncthreads();
    if (w != 0) return;

#pragma unroll
    for (int s = 1; s < 4; ++s) acc += *(const f32x4*)&S[s][l][0];

    float bv[4]; int bi[4]; float gap[4];
#pragma unroll
    for (int reg = 0; reg < 4; ++reg) {
        float v = acc[reg]; int i = lc; float s = -3.4e38f;
#pragma unroll
        for (int m = 1; m < 16; m <<= 1) {
            float ov = __shfl_xor(v, m, 64);
            int oi = __shfl_xor(i, m, 64);
            float os = __shfl_xor(s, m, 64);
            bool take = (ov > v) || (ov == v && oi < i);
            float loser = take ? v : ov;
            v = take ? ov : v;
            i = take ? oi : i;
            s = fmaxf(fmaxf(s, os), loser);
        }
        bv[reg] = v; bi[reg] = i; gap[reg] = v - s;
    }

    unsigned flagsw = 0;
#pragma unroll
    for (int reg = 0; reg < 4; ++reg)
        flagsw |= (gap[reg] < MARGIN ? 1u : 0u) << reg;

    if (__any(lc == 0 && flagsw != 0)) {   // rare exact path
#pragma unroll
        for (int reg = 0; reg < 4; ++reg) {
            for (int g = 0; g < 4; ++g) {
                const unsigned fw = __shfl(flagsw, g * 16, 64);
                if ((fw >> reg) & 1u) {
                    const int row = row0 + g * 4 + reg;
                    const float* xr = x + (size_t)row * DM;
                    float xv[16]; unsigned mk[16];
#pragma unroll
                    for (int k2 = 0; k2 < 16; ++k2) {
                        xv[k2] = xr[k2 * 64 + l];
                        mk[k2] = packT[k2 * 64 + l];
                    }
                    double best = 0.0; int bbi = 0;
                    for (int e = 0; e < 16; ++e) {
                        double a = 0.0;
#pragma unroll
                        for (int k2 = 0; k2 < 16; ++k2) {
                            const int pb = (int)((mk[k2] >> e) & 1u);
                            const int mb = (int)((mk[k2] >> (16 + e)) & 1u);
                            a += pb ? (double)xv[k2] : (mb ? -(double)xv[k2] : 0.0);
                        }
#pragma unroll
                        for (int m = 1; m < 64; m <<= 1) a += __shfl_xor(a, m, 64);
                        if (e == 0 || a > best) { best = a; bbi = e; }
                    }
                    if (lr == g && lc == 0) bi[reg] = bbi;
                }
            }
        }
    }

    if (lc == 0) {
#pragma unroll
        for (int reg = 0; reg < 4; ++reg) {
            const int row = row0 + lr * 4 + reg;
            idx[row] = bi[reg];
            outIdx[row] = (float)bi[reg];
            atomicAdd(&ctrl[bi[reg] * 16], 1u);
        }
    }
}

// Fused: blocks 0..127 build perm; blocks 128.. convert W f32 -> fp8 (x16
// scale; epilogue * 1/16) into the ks-interleaved layout:
// dest = (g & ~63) + ((g>>3)&3)*16 + ((g>>5)&1)*8   (g = 8-aligned elem idx).
__global__ __launch_bounds__(256) void k_permconv(const int* __restrict__ idx,
                                                  unsigned* __restrict__ ctrl,
                                                  int* __restrict__ perm,
                                                  const float* __restrict__ W,
                                                  unsigned char* __restrict__ W8) {
    if (blockIdx.x >= 128) {
        const size_t g = ((size_t)(blockIdx.x - 128) * 256 + threadIdx.x) * 8;
        float4 a = *(const float4*)&W[g];
        float4 b = *(const float4*)&W[g + 4];
        float f[8] = {a.x, a.y, a.z, a.w, b.x, b.y, b.z, b.w};
        unsigned long long p8 = 0ull;
#pragma unroll
        for (int j = 0; j < 8; ++j)
            p8 |= (unsigned long long)f2fp8(f[j] * 16.0f) << (8 * j);
        const size_t p = (g & ~(size_t)63) + ((g >> 3) & 3) * 16 + ((g >> 5) & 1) * 8;
        *(unsigned long long*)(W8 + p) = p8;
        return;
    }
    __shared__ unsigned hcnt[16];
    __shared__ unsigned hbase[16];
    const int t = threadIdx.x;
    const int row = blockIdx.x * 256 + t;
    int tb[NE + 1];
    tile_base(ctrl, tb);
    if (t < 16) hcnt[t] = 0;
    __syncthreads();
    const int e = idx[row];
    const unsigned lrank = atomicAdd(&hcnt[e], 1u);
    __syncthreads();
    if (t < 16) hbase[t] = atomicAdd(&ctrl[256 + t * 16], hcnt[t]);
    __syncthreads();
    perm[tb[e] * 128 + hbase[e] + lrank] = row;
}

// Grouped fp8 GEMM (R17): R7 iteration SHAPE verbatim — 8 ds_read_b128 at
// byte-identical swizzled addresses (conflict-free, measured 0 in R7), 4
// gload_lds16/thread/stage, vmcnt(4), 3 buffers depth-2, 1 barrier/iter,
// 48KB LDS -> 3 blk/CU — but fp8 rows (64B) with ks-interleaved chunks: each
// b128 read yields BOTH K-half fragments -> 32 MFMA/iter, NT=16 (half of R7).
// Clean discriminator: fixed-per-iteration cost -> ~2x; per-MFMA cost -> null.
__global__ __launch_bounds__(256) void k_gemm(
        const unsigned char* __restrict__ X8,
        const unsigned char* __restrict__ W8,
        const float* __restrict__ bias,
        const int* __restrict__ perm,
        const unsigned* __restrict__ ctrl,
        const float* __restrict__ x,
        float* __restrict__ out) {
    __shared__ unsigned char A_lds[3][8192];
    __shared__ unsigned char B_lds[3][8192];

    int tb[NE + 1];
    const int total = tile_base(ctrl, tb);

    int bx, ny;
    {
        const int flat = blockIdx.x;
        const int xcd = flat & 7, s2 = flat >> 3;
        bx = xcd * 34 + (s2 >> 3);
        ny = s2 & 7;
    }
    if (bx >= total) return;
    int e = 0;
    while (e < NE - 1 && tb[e + 1] <= bx) ++e;
    const int valid = (int)ctrl[e * 16] - (bx - tb[e]) * 128;  // 1..128
    const int n0 = ny * 128;

    const int t = threadIdx.x, w = t >> 6, l = t & 63;
    const int wr = w >> 1, wc = w & 1;
    const int lc = l & 15, lr = l >> 4;
    const int hsw = ((t & 3) - ((t >> 3) & 3)) & 3;   // staged 16B-chunk (as R7)
    const int ssw = (lr + (lc >> 1)) & 3;             // read slot (as R7)

    f32x4 acc[4][4];
#pragma unroll
    for (int m = 0; m < 4; ++m)
#pragma unroll
        for (int n = 0; n < 4; ++n) acc[m][n] = (f32x4){0.f, 0.f, 0.f, 0.f};

    const size_t aRowBase = (size_t)bx * 128;
    const unsigned char* Bg = W8 + ((size_t)e * DM + n0) * DM;

    const int r0 = t >> 2;
    const int prow0 = perm[aRowBase + r0];
    const int prow1 = perm[aRowBase + 64 + r0];
    const unsigned char* a0 = X8 + (size_t)prow0 * DM + hsw * 16;
    const unsigned char* a1 = X8 + (size_t)prow1 * DM + hsw * 16;
    const unsigned char* b0 = Bg + (size_t)r0 * DM + hsw * 16;
    const unsigned char* b1 = Bg + (size_t)(64 + r0) * DM + hsw * 16;

    auto STAGE = [&](int kt, int buf) {   // 4 VMEM ops/thread (as R7)
        const int ko = kt * 64;
        gload_lds16(a0 + ko, &A_lds[buf][w * 1024]);
        gload_lds16(a1 + ko, &A_lds[buf][4096 + w * 1024]);
        gload_lds16(b0 + ko, &B_lds[buf][w * 1024]);
        gload_lds16(b1 + ko, &B_lds[buf][4096 + w * 1024]);
    };

    STAGE(0, 0);
    STAGE(1, 1);

    const int NT = DM / 64;  // 16
    int cur = 0;
    for (int kt = 0; kt < NT; ++kt) {
        if (kt + 1 < NT) asm volatile("s_waitcnt vmcnt(4)" ::: "memory");
        else             asm volatile("s_waitcnt vmcnt(0)" ::: "memory");
        __builtin_amdgcn_sched_barrier(0);
        __builtin_amdgcn_s_barrier();
        __builtin_amdgcn_sched_barrier(0);

        if (kt + 2 < NT) {
            const int nb = (cur + 2 >= 3) ? cur - 1 : cur + 2;
            STAGE(kt + 2, nb);
        }

        lx2 af[4], bf[4];   // each b128 = {ks0 frag, ks1 frag} for this lane
#pragma unroll
        for (int m = 0; m < 4; ++m)
            af[m] = *(const lx2*)&A_lds[cur][(wr * 64 + m * 16 + lc) * 64 + ssw * 16];
#pragma unroll
        for (int n = 0; n < 4; ++n)
            bf[n] = *(const lx2*)&B_lds[cur][(wc * 64 + n * 16 + lc) * 64 + ssw * 16];
#pragma unroll
        for (int m = 0; m < 4; ++m)
#pragma unroll
            for (int n = 0; n < 4; ++n) {
                acc[m][n] = MFMAF8(af[m].x, bf[n].x, acc[m][n]);
                acc[m][n] = MFMAF8(af[m].y, bf[n].y, acc[m][n]);
            }

        cur = (cur + 1 >= 3) ? 0 : cur + 1;
    }

    float bvv[4];
#pragma unroll
    for (int n = 0; n < 4; ++n) bvv[n] = bias[e * DM + n0 + wc * 64 + n * 16 + lc];

#pragma unroll
    for (int m = 0; m < 4; ++m) {
#pragma unroll
        for (int reg = 0; reg < 4; ++reg) {
            const int rit = wr * 64 + m * 16 + lr * 4 + reg;
            if (rit < valid) {
                const int orow = perm[aRowBase + rit];
                float* op = out + (size_t)orow * DM;
                const float* xr = x + (size_t)orow * DM;
#pragma unroll
                for (int n = 0; n < 4; ++n) {
                    const int col = n0 + wc * 64 + n * 16 + lc;
                    float v = acc[m][n][reg] * 0.0625f + bvv[n];
                    v = v > 0.f ? v : 0.f;
                    op[col] = v + xr[col];
                }
            }
        }
    }
}

// Fallback (small ws): 128x128 2-phase reg-staged f32->bf16.
__global__ __launch_bounds__(256) void k_gemm_small(
        const float* __restrict__ x, const float* __restrict__ W,
        const float* __restrict__ bias, const int* __restrict__ perm,
        const unsigned* __restrict__ ctrl, float* __restrict__ out) {
    __shared__ unsigned short A_lds[128 * 32];
    __shared__ unsigned short B_lds[128 * 32];
    int tb[NE + 1];
    const int total = tile_base(ctrl, tb);
    int bx, ny;
    {
        const int flat = blockIdx.x;
        const int xcd = flat & 7, s2 = flat >> 3;
        bx = xcd * 34 + (s2 >> 3);
        ny = s2 & 7;
    }
    if (bx >= total) return;
    int e = 0;
    while (e < NE - 1 && tb[e + 1] <= bx) ++e;
    const int valid = (int)ctrl[e * 16] - (bx - tb[e]) * 128;
    const int n0 = ny * 128;
    const int t = threadIdx.x, w = t >> 6, l = t & 63;
    const int wr = w >> 1, wc = w & 1;
    const int lc = l & 15, lr = l >> 4;
    const int hsw = ((t & 3) - ((t >> 3) & 3)) & 3;
    const int ssw = (lr + (lc >> 1)) & 3;

    f32x4 acc[4][4];
#pragma unroll
    for (int m = 0; m < 4; ++m)
#pragma unroll
        for (int n = 0; n < 4; ++n) acc[m][n] = (f32x4){0.f, 0.f, 0.f, 0.f};
    const size_t aRowBase = (size_t)bx * 128;

    for (int kt = 0; kt < DM / 32; ++kt) {
        __syncthreads();
#pragma unroll
        for (int rd = 0; rd < 2; ++rd) {
            const int c = rd * 256 + t;
            const int r = c >> 2;
            const float* wp = W + ((size_t)e * DM + n0 + r) * DM + kt * 32 + hsw * 8;
            float4 q0 = *(const float4*)wp;
            float4 q1 = *(const float4*)(wp + 4);
            *(ushort4*)&B_lds[c * 8]     = make_ushort4(f2bf(q0.x), f2bf(q0.y), f2bf(q0.z), f2bf(q0.w));
            *(ushort4*)&B_lds[c * 8 + 4] = make_ushort4(f2bf(q1.x), f2bf(q1.y), f2bf(q1.z), f2bf(q1.w));
            ushort4 p0 = make_ushort4(0, 0, 0, 0), p1 = p0;
            if (r < valid) {
                const int orow = perm[aRowBase + r];
                const float* xp = x + (size_t)orow * DM + kt * 32 + hsw * 8;
                float4 u0 = *(const float4*)xp;
                float4 u1 = *(const float4*)(xp + 4);
                p0 = make_ushort4(f2bf(u0.x), f2bf(u0.y), f2bf(u0.z), f2bf(u0.w));
                p1 = make_ushort4(f2bf(u1.x), f2bf(u1.y), f2bf(u1.z), f2bf(u1.w));
            }
            *(ushort4*)&A_lds[c * 8]     = p0;
            *(ushort4*)&A_lds[c * 8 + 4] = p1;
        }
        __syncthreads();
        bf16x8 af[4], bf[4];
#pragma unroll
        for (int m = 0; m < 4; ++m)
            af[m] = *(const bf16x8*)&A_lds[(wr * 64 + m * 16 + lc) * 32 + ssw * 8];
#pragma unroll
        for (int n = 0; n < 4; ++n)
            bf[n] = *(const bf16x8*)&B_lds[(wc * 64 + n * 16 + lc) * 32 + ssw * 8];
#pragma unroll
        for (int m = 0; m < 4; ++m)
#pragma unroll
            for (int n = 0; n < 4; ++n)
                acc[m][n] = MFMA16(af[m], bf[n], acc[m][n]);
    }

    float bvv[4];
#pragma unroll
    for (int n = 0; n < 4; ++n) bvv[n] = bias[e * DM + n0 + wc * 64 + n * 16 + lc];
#pragma unroll
    for (int m = 0; m < 4; ++m)
#pragma unroll
        for (int reg = 0; reg < 4; ++reg) {
            const int rit = wr * 64 + m * 16 + lr * 4 + reg;
            if (rit < valid) {
                const int orow = perm[aRowBase + rit];
                const float* xr = x + (size_t)orow * DM;
                float* op = out + (size_t)orow * DM;
#pragma unroll
                for (int n = 0; n < 4; ++n) {
                    const int col = n0 + wc * 64 + n * 16 + lc;
                    float v = acc[m][n][reg] + bvv[n];
                    v = v > 0.f ? v : 0.f;
                    op[col] = v + xr[col];
                }
            }
        }
}

extern "C" void kernel_launch(void* const* d_in, const int* in_sizes, int n_in,
                              void* d_out, int out_size, void* d_ws, size_t ws_size,
                              hipStream_t stream) {
    const float* x    = (const float*)d_in[0];
    const float* sig  = (const float*)d_in[1];
    const float* W    = (const float*)d_in[2];
    const float* bias = (const float*)d_in[3];
    float* out = (float*)d_out;
    float* outIdx = out + (size_t)BATCH * DM;

    char* ws = (char*)d_ws;
    int* idx = (int*)ws;
    unsigned* ctrl = (unsigned*)(ws + CTRL_OFF);
    unsigned short* Qbf = (unsigned short*)(ws + QBF_OFF);
    int* perm = (int*)(ws + PERM_OFF);
    unsigned char* X8 = (unsigned char*)(ws + X8_OFF);
    unsigned char* W8 = (unsigned char*)(ws + W8_OFF);

    const bool full = ws_size >= WS_NEED;

    k_init<<<64, 256, 0, stream>>>(sig, ctrl, perm, Qbf);
    k_router<<<2048, 256, 0, stream>>>(x, Qbf, ctrl, idx, outIdx, X8, full ? 1 : 0);
    k_permconv<<<full ? 8320 : 128, 256, 0, stream>>>(idx, ctrl, perm, W, W8);
    if (full) {
        k_gemm<<<2176, 256, 0, stream>>>(X8, W8, bias, perm, ctrl, x, out);
    } else {
        k_gemm_small<<<2176, 256, 0, stream>>>(x, W, bias, perm, ctrl, out);
    }
}

// Round 18
// 215.625 us; speedup vs baseline: 1.0370x; 1.0073x over previous
//
#include <hip/hip_runtime.h>
#include <hip/hip_bf16.h>

#define BATCH   32768
#define DM      1024
#define NE      16
#define THRESHF 0.3f
#define MARGIN  0.02f

// ws layout (bytes)
// idx   @ 0          : int32[32768]
// ctrl  @ 131072     : u32[2048]  (counts | cursor | packT)
// Qbf   @ 139264     : bf16[16*1024] ternary
// perm  @ 172032     : int32[36864] (prefilled 0)
// X8    @ 319488     : fp8[32768*1024]  ks-interleaved rows
// W8    @ 33873920   : fp8[16*1024*1024] ks-interleaved rows (ends ~50.7 MB)
#define CTRL_OFF 131072
#define QBF_OFF  139264
#define PERM_OFF 172032
#define X8_OFF   319488
#define W8_OFF   33873920ull
#define WS_NEED  (W8_OFF + (size_t)NE * DM * DM)

typedef __attribute__((ext_vector_type(8))) short bf16x8;
typedef __attribute__((ext_vector_type(4))) float f32x4;
typedef __attribute__((ext_vector_type(2))) long lx2;

#define MFMA16(a, b, c)  __builtin_amdgcn_mfma_f32_16x16x32_bf16(a, b, c, 0, 0, 0)
#define MFMAF8(a, b, c)  __builtin_amdgcn_mfma_f32_16x16x32_fp8_fp8(a, b, c, 0, 0, 0)

static __device__ __forceinline__ unsigned short f2bf(float f) {
    union { float f; unsigned u; } v; v.f = f;
    unsigned r = (v.u + 0x7FFFu + ((v.u >> 16) & 1u)) >> 16;  // RNE
    return (unsigned short)r;
}
static __device__ __forceinline__ float bf2f(unsigned short h) {
    union { unsigned u; float f; } v; v.u = ((unsigned)h) << 16;
    return v.f;
}

// f32 -> fp8 e4m3fn (OCP), RNE, saturate to 448, correct subnormals.
static __device__ __forceinline__ unsigned f2fp8(float f) {
    union { float f; unsigned u; } v; v.f = f;
    const unsigned s = (v.u >> 24) & 0x80u;
    const float a = __builtin_fabsf(f);
    if (a >= 448.0f) return s | 0x7Eu;
    if (a < 0.015625f) {
        const int n = (int)rintf(a * 512.0f);
        return s | (unsigned)n;
    }
    unsigned u = v.u;
    u += 0x7FFFFu + ((u >> 20) & 1u);
    const int e = (int)((u >> 23) & 0xFF) - 127;
    const unsigned m = (u >> 20) & 7u;
    return s | ((unsigned)(e + 7) << 3) | m;
}

static __device__ __forceinline__ void gload_lds16(const void* g, void* s) {
    __builtin_amdgcn_global_load_lds(
        (const __attribute__((address_space(1))) void*)g,
        (__attribute__((address_space(3))) void*)s, 16, 0, 0);
}

// Local tile-base from final counts: 16 adds.
static __device__ __forceinline__ int tile_base(const unsigned* ctrl, int* tb) {
    int acc = 0;
#pragma unroll
    for (int e = 0; e < NE; ++e) {
        tb[e] = acc;
        acc += (int)((ctrl[e * 16] + 127u) >> 7);
    }
    tb[NE] = acc;
    return acc;
}

// Zero ctrl, build ternary pack table + bf16 ternary Q, prefill perm with 0.
__global__ void k_init(const float* __restrict__ sig, unsigned* __restrict__ ctrl,
                       int* __restrict__ perm, unsigned short* __restrict__ Qbf) {
    const int t = blockIdx.x * 256 + threadIdx.x;  // 0..16383
    if (t < 544) ctrl[t] = 0;
    if (t < 1024) {
        unsigned pm = 0, mm = 0;
#pragma unroll
        for (int e = 0; e < NE; ++e) {
            float s = sig[e * DM + t];
            pm |= (s > THRESHF ? 1u : 0u) << e;
            mm |= (s < -THRESHF ? 1u : 0u) << e;
        }
        ctrl[1024 + t] = pm | (mm << 16);
    }
    if (t < 9216) ((int4*)perm)[t] = make_int4(0, 0, 0, 0);
    {
        float s = sig[t];
        Qbf[t] = s > THRESHF ? (unsigned short)0x3F80u
                             : (s < -THRESHF ? (unsigned short)0xBF80u : (unsigned short)0u);
    }
}

// Split-K MFMA router (R11 structure; Qbf table). R18: X8 stores combined to
// one 16B/lane store per kt (full 64B lines per 4 lanes) — kills the 2x
// write amplification measured through R17 (WRITE ~70MB for a 33MB buffer).
__global__ __launch_bounds__(256) void k_router(const float* __restrict__ x,
                                                const unsigned short* __restrict__ Qbf,
                                                unsigned* __restrict__ ctrl,
                                                int* __restrict__ idx,
                                                float* __restrict__ outIdx,
                                                unsigned char* __restrict__ X8,
                                                int writeX8) {
    __shared__ float S[4][64][4];
    const int t = threadIdx.x, w = t >> 6, l = t & 63;
    const int lc = l & 15, lr = l >> 4;
    const int row0 = blockIdx.x * 16;
    const unsigned* packT = ctrl + 1024;

    const float* ax = x + (size_t)(row0 + lc) * DM + lr * 8;
    const unsigned short* qx = Qbf + (size_t)lc * DM + lr * 8;
    unsigned char* xb = X8 + (size_t)(row0 + lc) * DM + lr * 16;  // permuted base

    f32x4 acc = (f32x4){0.f, 0.f, 0.f, 0.f};

    for (int kt = w * 4; kt < w * 4 + 4; ++kt) {
        unsigned long long p8s[2];
#pragma unroll
        for (int h = 0; h < 2; ++h) {
            const int ko = kt * 64 + h * 32;
            float4 v0 = *(const float4*)(ax + ko);
            float4 v1 = *(const float4*)(ax + ko + 4);
            bf16x8 q = *(const bf16x8*)(qx + ko);

            float f[8] = {v0.x, v0.y, v0.z, v0.w, v1.x, v1.y, v1.z, v1.w};
            bf16x8 ah, al;
            unsigned long long p8 = 0ull;
#pragma unroll
            for (int j = 0; j < 8; ++j) {
                unsigned short hi = f2bf(f[j]);
                float r = f[j] - bf2f(hi);
                ah[j] = (short)hi;
                al[j] = (short)f2bf(r);
                p8 |= (unsigned long long)f2fp8(f[j]) << (8 * j);
            }
            p8s[h] = p8;
            acc = MFMA16(ah, q, acc);
            acc = MFMA16(al, q, acc);
        }
        if (writeX8) {
            lx2 st;
            st.x = (long)p8s[0];
            st.y = (long)p8s[1];
            *(lx2*)(xb + kt * 64) = st;   // 16B/lane: ks0 || ks1, full lines
        }
    }

    *(f32x4*)&S[w][l][0] = acc;
    __syncthreads();
    if (w != 0) return;

#pragma unroll
    for (int s = 1; s < 4; ++s) acc += *(const f32x4*)&S[s][l][0];

    float bv[4]; int bi[4]; float gap[4];
#pragma unroll
    for (int reg = 0; reg < 4; ++reg) {
        float v = acc[reg]; int i = lc; float s = -3.4e38f;
#pragma unroll
        for (int m = 1; m < 16; m <<= 1) {
            float ov = __shfl_xor(v, m, 64);
            int oi = __shfl_xor(i, m, 64);
            float os = __shfl_xor(s, m, 64);
            bool take = (ov > v) || (ov == v && oi < i);
            float loser = take ? v : ov;
            v = take ? ov : v;
            i = take ? oi : i;
            s = fmaxf(fmaxf(s, os), loser);
        }
        bv[reg] = v; bi[reg] = i; gap[reg] = v - s;
    }

    unsigned flagsw = 0;
#pragma unroll
    for (int reg = 0; reg < 4; ++reg)
        flagsw |= (gap[reg] < MARGIN ? 1u : 0u) << reg;

    if (__any(lc == 0 && flagsw != 0)) {   // rare exact path
#pragma unroll
        for (int reg = 0; reg < 4; ++reg) {
            for (int g = 0; g < 4; ++g) {
                const unsigned fw = __shfl(flagsw, g * 16, 64);
                if ((fw >> reg) & 1u) {
                    const int row = row0 + g * 4 + reg;
                    const float* xr = x + (size_t)row * DM;
                    float xv[16]; unsigned mk[16];
#pragma unroll
                    for (int k2 = 0; k2 < 16; ++k2) {
                        xv[k2] = xr[k2 * 64 + l];
                        mk[k2] = packT[k2 * 64 + l];
                    }
                    double best = 0.0; int bbi = 0;
                    for (int e = 0; e < 16; ++e) {
                        double a = 0.0;
#pragma unroll
                        for (int k2 = 0; k2 < 16; ++k2) {
                            const int pb = (int)((mk[k2] >> e) & 1u);
                            const int mb = (int)((mk[k2] >> (16 + e)) & 1u);
                            a += pb ? (double)xv[k2] : (mb ? -(double)xv[k2] : 0.0);
                        }
#pragma unroll
                        for (int m = 1; m < 64; m <<= 1) a += __shfl_xor(a, m, 64);
                        if (e == 0 || a > best) { best = a; bbi = e; }
                    }
                    if (lr == g && lc == 0) bi[reg] = bbi;
                }
            }
        }
    }

    if (lc == 0) {
#pragma unroll
        for (int reg = 0; reg < 4; ++reg) {
            const int row = row0 + lr * 4 + reg;
            idx[row] = bi[reg];
            outIdx[row] = (float)bi[reg];
            atomicAdd(&ctrl[bi[reg] * 16], 1u);
        }
    }
}

// Fused: blocks 0..127 build perm; blocks 128.. convert W f32 -> fp8 (x16
// scale; epilogue * 1/16) into the ks-interleaved layout.
__global__ __launch_bounds__(256) void k_permconv(const int* __restrict__ idx,
                                                  unsigned* __restrict__ ctrl,
                                                  int* __restrict__ perm,
                                                  const float* __restrict__ W,
                                                  unsigned char* __restrict__ W8) {
    if (blockIdx.x >= 128) {
        const size_t g = ((size_t)(blockIdx.x - 128) * 256 + threadIdx.x) * 8;
        float4 a = *(const float4*)&W[g];
        float4 b = *(const float4*)&W[g + 4];
        float f[8] = {a.x, a.y, a.z, a.w, b.x, b.y, b.z, b.w};
        unsigned long long p8 = 0ull;
#pragma unroll
        for (int j = 0; j < 8; ++j)
            p8 |= (unsigned long long)f2fp8(f[j] * 16.0f) << (8 * j);
        const size_t p = (g & ~(size_t)63) + ((g >> 3) & 3) * 16 + ((g >> 5) & 1) * 8;
        *(unsigned long long*)(W8 + p) = p8;
        return;
    }
    __shared__ unsigned hcnt[16];
    __shared__ unsigned hbase[16];
    const int t = threadIdx.x;
    const int row = blockIdx.x * 256 + t;
    int tb[NE + 1];
    tile_base(ctrl, tb);
    if (t < 16) hcnt[t] = 0;
    __syncthreads();
    const int e = idx[row];
    const unsigned lrank = atomicAdd(&hcnt[e], 1u);
    __syncthreads();
    if (t < 16) hbase[t] = atomicAdd(&ctrl[256 + t * 16], hcnt[t]);
    __syncthreads();
    perm[tb[e] * 128 + hbase[e] + lrank] = row;
}

// Grouped fp8 GEMM (R17, proven 137us): R7 iteration shape with fp8 64B rows,
// ks-interleaved chunks; 8 ds_read_b128 (conflict-free), 4 gload_lds16/thr,
// vmcnt(4), 3 buffers depth-2, 1 barrier/iter, 48KB LDS, 32 MFMA/iter, NT=16.
__global__ __launch_bounds__(256) void k_gemm(
        const unsigned char* __restrict__ X8,
        const unsigned char* __restrict__ W8,
        const float* __restrict__ bias,
        const int* __restrict__ perm,
        const unsigned* __restrict__ ctrl,
        const float* __restrict__ x,
        float* __restrict__ out) {
    __shared__ unsigned char A_lds[3][8192];
    __shared__ unsigned char B_lds[3][8192];

    int tb[NE + 1];
    const int total = tile_base(ctrl, tb);

    int bx, ny;
    {
        const int flat = blockIdx.x;
        const int xcd = flat & 7, s2 = flat >> 3;
        bx = xcd * 34 + (s2 >> 3);
        ny = s2 & 7;
    }
    if (bx >= total) return;
    int e = 0;
    while (e < NE - 1 && tb[e + 1] <= bx) ++e;
    const int valid = (int)ctrl[e * 16] - (bx - tb[e]) * 128;  // 1..128
    const int n0 = ny * 128;

    const int t = threadIdx.x, w = t >> 6, l = t & 63;
    const int wr = w >> 1, wc = w & 1;
    const int lc = l & 15, lr = l >> 4;
    const int hsw = ((t & 3) - ((t >> 3) & 3)) & 3;
    const int ssw = (lr + (lc >> 1)) & 3;

    f32x4 acc[4][4];
#pragma unroll
    for (int m = 0; m < 4; ++m)
#pragma unroll
        for (int n = 0; n < 4; ++n) acc[m][n] = (f32x4){0.f, 0.f, 0.f, 0.f};

    const size_t aRowBase = (size_t)bx * 128;
    const unsigned char* Bg = W8 + ((size_t)e * DM + n0) * DM;

    const int r0 = t >> 2;
    const int prow0 = perm[aRowBase + r0];
    const int prow1 = perm[aRowBase + 64 + r0];
    const unsigned char* a0 = X8 + (size_t)prow0 * DM + hsw * 16;
    const unsigned char* a1 = X8 + (size_t)prow1 * DM + hsw * 16;
    const unsigned char* b0 = Bg + (size_t)r0 * DM + hsw * 16;
    const unsigned char* b1 = Bg + (size_t)(64 + r0) * DM + hsw * 16;

    auto STAGE = [&](int kt, int buf) {   // 4 VMEM ops/thread
        const int ko = kt * 64;
        gload_lds16(a0 + ko, &A_lds[buf][w * 1024]);
        gload_lds16(a1 + ko, &A_lds[buf][4096 + w * 1024]);
        gload_lds16(b0 + ko, &B_lds[buf][w * 1024]);
        gload_lds16(b1 + ko, &B_lds[buf][4096 + w * 1024]);
    };

    STAGE(0, 0);
    STAGE(1, 1);

    const int NT = DM / 64;  // 16
    int cur = 0;
    for (int kt = 0; kt < NT; ++kt) {
        if (kt + 1 < NT) asm volatile("s_waitcnt vmcnt(4)" ::: "memory");
        else             asm volatile("s_waitcnt vmcnt(0)" ::: "memory");
        __builtin_amdgcn_sched_barrier(0);
        __builtin_amdgcn_s_barrier();
        __builtin_amdgcn_sched_barrier(0);

        if (kt + 2 < NT) {
            const int nb = (cur + 2 >= 3) ? cur - 1 : cur + 2;
            STAGE(kt + 2, nb);
        }

        lx2 af[4], bf[4];
#pragma unroll
        for (int m = 0; m < 4; ++m)
            af[m] = *(const lx2*)&A_lds[cur][(wr * 64 + m * 16 + lc) * 64 + ssw * 16];
#pragma unroll
        for (int n = 0; n < 4; ++n)
            bf[n] = *(const lx2*)&B_lds[cur][(wc * 64 + n * 16 + lc) * 64 + ssw * 16];
#pragma unroll
        for (int m = 0; m < 4; ++m)
#pragma unroll
            for (int n = 0; n < 4; ++n) {
                acc[m][n] = MFMAF8(af[m].x, bf[n].x, acc[m][n]);
                acc[m][n] = MFMAF8(af[m].y, bf[n].y, acc[m][n]);
            }

        cur = (cur + 1 >= 3) ? 0 : cur + 1;
    }

    float bvv[4];
#pragma unroll
    for (int n = 0; n < 4; ++n) bvv[n] = bias[e * DM + n0 + wc * 64 + n * 16 + lc];

#pragma unroll
    for (int m = 0; m < 4; ++m) {
#pragma unroll
        for (int reg = 0; reg < 4; ++reg) {
            const int rit = wr * 64 + m * 16 + lr * 4 + reg;
            if (rit < valid) {
                const int orow = perm[aRowBase + rit];
                float* op = out + (size_t)orow * DM;
                const float* xr = x + (size_t)orow * DM;
#pragma unroll
                for (int n = 0; n < 4; ++n) {
                    const int col = n0 + wc * 64 + n * 16 + lc;
                    float v = acc[m][n][reg] * 0.0625f + bvv[n];
                    v = v > 0.f ? v : 0.f;
                    op[col] = v + xr[col];
                }
            }
        }
    }
}

// Fallback (small ws): 128x128 2-phase reg-staged f32->bf16.
__global__ __launch_bounds__(256) void k_gemm_small(
        const float* __restrict__ x, const float* __restrict__ W,
        const float* __restrict__ bias, const int* __restrict__ perm,
        const unsigned* __restrict__ ctrl, float* __restrict__ out) {
    __shared__ unsigned short A_lds[128 * 32];
    __shared__ unsigned short B_lds[128 * 32];
    int tb[NE + 1];
    const int total = tile_base(ctrl, tb);
    int bx, ny;
    {
        const int flat = blockIdx.x;
        const int xcd = flat & 7, s2 = flat >> 3;
        bx = xcd * 34 + (s2 >> 3);
        ny = s2 & 7;
    }
    if (bx >= total) return;
    int e = 0;
    while (e < NE - 1 && tb[e + 1] <= bx) ++e;
    const int valid = (int)ctrl[e * 16] - (bx - tb[e]) * 128;
    const int n0 = ny * 128;
    const int t = threadIdx.x, w = t >> 6, l = t & 63;
    const int wr = w >> 1, wc = w & 1;
    const int lc = l & 15, lr = l >> 4;
    const int hsw = ((t & 3) - ((t >> 3) & 3)) & 3;
    const int ssw = (lr + (lc >> 1)) & 3;

    f32x4 acc[4][4];
#pragma unroll
    for (int m = 0; m < 4; ++m)
#pragma unroll
        for (int n = 0; n < 4; ++n) acc[m][n] = (f32x4){0.f, 0.f, 0.f, 0.f};
    const size_t aRowBase = (size_t)bx * 128;

    for (int kt = 0; kt < DM / 32; ++kt) {
        __syncthreads();
#pragma unroll
        for (int rd = 0; rd < 2; ++rd) {
            const int c = rd * 256 + t;
            const int r = c >> 2;
            const float* wp = W + ((size_t)e * DM + n0 + r) * DM + kt * 32 + hsw * 8;
            float4 q0 = *(const float4*)wp;
            float4 q1 = *(const float4*)(wp + 4);
            *(ushort4*)&B_lds[c * 8]     = make_ushort4(f2bf(q0.x), f2bf(q0.y), f2bf(q0.z), f2bf(q0.w));
            *(ushort4*)&B_lds[c * 8 + 4] = make_ushort4(f2bf(q1.x), f2bf(q1.y), f2bf(q1.z), f2bf(q1.w));
            ushort4 p0 = make_ushort4(0, 0, 0, 0), p1 = p0;
            if (r < valid) {
                const int orow = perm[aRowBase + r];
                const float* xp = x + (size_t)orow * DM + kt * 32 + hsw * 8;
                float4 u0 = *(const float4*)xp;
                float4 u1 = *(const float4*)(xp + 4);
                p0 = make_ushort4(f2bf(u0.x), f2bf(u0.y), f2bf(u0.z), f2bf(u0.w));
                p1 = make_ushort4(f2bf(u1.x), f2bf(u1.y), f2bf(u1.z), f2bf(u1.w));
            }
            *(ushort4*)&A_lds[c * 8]     = p0;
            *(ushort4*)&A_lds[c * 8 + 4] = p1;
        }
        __syncthreads();
        bf16x8 af[4], bf[4];
#pragma unroll
        for (int m = 0; m < 4; ++m)
            af[m] = *(const bf16x8*)&A_lds[(wr * 64 + m * 16 + lc) * 32 + ssw * 8];
#pragma unroll
        for (int n = 0; n < 4; ++n)
            bf[n] = *(const bf16x8*)&B_lds[(wc * 64 + n * 16 + lc) * 32 + ssw * 8];
#pragma unroll
        for (int m = 0; m < 4; ++m)
#pragma unroll
            for (int n = 0; n < 4; ++n)
                acc[m][n] = MFMA16(af[m], bf[n], acc[m][n]);
    }

    float bvv[4];
#pragma unroll
    for (int n = 0; n < 4; ++n) bvv[n] = bias[e * DM + n0 + wc * 64 + n * 16 + lc];
#pragma unroll
    for (int m = 0; m < 4; ++m)
#pragma unroll
        for (int reg = 0; reg < 4; ++reg) {
            const int rit = wr * 64 + m * 16 + lr * 4 + reg;
            if (rit < valid) {
                const int orow = perm[aRowBase + rit];
                const float* xr = x + (size_t)orow * DM;
                float* op = out + (size_t)orow * DM;
#pragma unroll
                for (int n = 0; n < 4; ++n) {
                    const int col = n0 + wc * 64 + n * 16 + lc;
                    float v = acc[m][n][reg] + bvv[n];
                    v = v > 0.f ? v : 0.f;
                    op[col] = v + xr[col];
                }
            }
        }
}

extern "C" void kernel_launch(void* const* d_in, const int* in_sizes, int n_in,
                              void* d_out, int out_size, void* d_ws, size_t ws_size,
                              hipStream_t stream) {
    const float* x    = (const float*)d_in[0];
    const float* sig  = (const float*)d_in[1];
    const float* W    = (const float*)d_in[2];
    const float* bias = (const float*)d_in[3];
    float* out = (float*)d_out;
    float* outIdx = out + (size_t)BATCH * DM;

    char* ws = (char*)d_ws;
    int* idx = (int*)ws;
    unsigned* ctrl = (unsigned*)(ws + CTRL_OFF);
    unsigned short* Qbf = (unsigned short*)(ws + QBF_OFF);
    int* perm = (int*)(ws + PERM_OFF);
    unsigned char* X8 = (unsigned char*)(ws + X8_OFF);
    unsigned char* W8 = (unsigned char*)(ws + W8_OFF);

    const bool full = ws_size >= WS_NEED;

    k_init<<<64, 256, 0, stream>>>(sig, ctrl, perm, Qbf);
    k_router<<<2048, 256, 0, stream>>>(x, Qbf, ctrl, idx, outIdx, X8, full ? 1 : 0);
    k_permconv<<<full ? 8320 : 128, 256, 0, stream>>>(idx, ctrl, perm, W, W8);
    if (full) {
        k_gemm<<<2176, 256, 0, stream>>>(X8, W8, bias, perm, ctrl, x, out);
    } else {
        k_gemm_small<<<2176, 256, 0, stream>>>(x, W, bias, perm, ctrl, out);
    }
}